// Round 1
// baseline (153.826 us; speedup 1.0000x reference)
//
#include <hip/hip_runtime.h>
#include <math.h>

#define NB  8
#define NH  3
#define NP  4096
#define BLK 256
#define TQ  512

// out[0] = 25 * sum_b || N_b N_b^T - I ||_F   (N_b rows are unit normals)
__global__ void reg_kernel(const float* __restrict__ planes, float* __restrict__ out) {
    int b = threadIdx.x;
    float r = 0.0f;
    if (b < NB) {
        float n[NH][3];
        for (int h = 0; h < NH; ++h) {
            const float* pl = planes + (b * NH + h) * 4;
            float a0 = pl[0], a1 = pl[1], a2 = pl[2];
            float inv = 1.0f / sqrtf(a0 * a0 + a1 * a1 + a2 * a2);
            n[h][0] = a0 * inv; n[h][1] = a1 * inv; n[h][2] = a2 * inv;
        }
        float fro = 0.0f;
        for (int i = 0; i < NH; ++i)
            for (int j = 0; j < NH; ++j) {
                float d = n[i][0] * n[j][0] + n[i][1] * n[j][1] + n[i][2] * n[j][2]
                          - (i == j ? 1.0f : 0.0f);
                fro += d * d;
            }
        r = sqrtf(fro);
    }
    for (int o = 32; o > 0; o >>= 1) r += __shfl_down(r, o);
    if (threadIdx.x == 0) out[0] = 25.0f * r;
}

// grid: x = p-tile (NP/BLK), y = b*NH+h (24), z = dir (0: rows=x cols=refl, 1: rows=refl cols=x)
// Each thread owns one row point; row-min kept in registers; columns staged in LDS as
// float4(-2*c0, -2*c1, -2*c2, |c|^2) so each pair is 3 fma + 1 min.
__global__ void __launch_bounds__(BLK) chamfer_kernel(const float* __restrict__ pts,
                                                      const float* __restrict__ planes,
                                                      float* __restrict__ out) {
    __shared__ float4 qs[TQ];
    __shared__ float wsum[BLK / 64];

    const int bh  = blockIdx.y;
    const int b   = bh / NH;
    const int h   = bh - b * NH;
    const int dir = blockIdx.z;

    const float* pl = planes + (b * NH + h) * 4;
    float n0 = pl[0], n1 = pl[1], n2 = pl[2], off = pl[3];
    float inv = 1.0f / sqrtf(n0 * n0 + n1 * n1 + n2 * n2);
    n0 *= inv; n1 *= inv; n2 *= inv;

    const float* bp = pts + (size_t)b * NP * 3;

    const int p = blockIdx.x * BLK + threadIdx.x;
    float x0 = bp[p * 3 + 0], x1 = bp[p * 3 + 1], x2 = bp[p * 3 + 2];
    if (dir) {  // rows are the reflected set
        float t = 2.0f * (n0 * x0 + n1 * x1 + n2 * x2 + off);
        x0 -= t * n0; x1 -= t * n1; x2 -= t * n2;
    }
    const float xsq = x0 * x0 + x1 * x1 + x2 * x2;

    float m0 = 1e30f, m1 = 1e30f, m2 = 1e30f, m3 = 1e30f;

    for (int q0 = 0; q0 < NP; q0 += TQ) {
        __syncthreads();
        for (int i = threadIdx.x; i < TQ; i += BLK) {
            const int q = q0 + i;
            float y0 = bp[q * 3 + 0], y1 = bp[q * 3 + 1], y2 = bp[q * 3 + 2];
            if (!dir) {  // columns are the reflected set
                float t = 2.0f * (n0 * y0 + n1 * y1 + n2 * y2 + off);
                y0 -= t * n0; y1 -= t * n1; y2 -= t * n2;
            }
            float ysq = y0 * y0 + y1 * y1 + y2 * y2;
            qs[i] = make_float4(-2.0f * y0, -2.0f * y1, -2.0f * y2, ysq);
        }
        __syncthreads();
        #pragma unroll 4
        for (int i = 0; i < TQ; i += 4) {
            float4 a = qs[i], bq = qs[i + 1], c = qs[i + 2], d = qs[i + 3];
            float t0 = fmaf(x2, a.z,  fmaf(x1, a.y,  fmaf(x0, a.x,  a.w)));
            float t1 = fmaf(x2, bq.z, fmaf(x1, bq.y, fmaf(x0, bq.x, bq.w)));
            float t2 = fmaf(x2, c.z,  fmaf(x1, c.y,  fmaf(x0, c.x,  c.w)));
            float t3 = fmaf(x2, d.z,  fmaf(x1, d.y,  fmaf(x0, d.x,  d.w)));
            m0 = fminf(m0, t0); m1 = fminf(m1, t1);
            m2 = fminf(m2, t2); m3 = fminf(m3, t3);
        }
    }
    // max(d,0) commutes with min over q, so clamp once per row.
    float rv = fmaxf(xsq + fminf(fminf(m0, m1), fminf(m2, m3)), 0.0f);

    // block-reduce the per-row minima
    for (int o = 32; o > 0; o >>= 1) rv += __shfl_down(rv, o);
    const int wid = threadIdx.x >> 6;
    if ((threadIdx.x & 63) == 0) wsum[wid] = rv;
    __syncthreads();
    if (threadIdx.x == 0) {
        float s = wsum[0] + wsum[1] + wsum[2] + wsum[3];
        atomicAdd(out, s * (1.0f / (float)(NB * NP)));  // mean over (B,P)
    }
}

extern "C" void kernel_launch(void* const* d_in, const int* in_sizes, int n_in,
                              void* d_out, int out_size, void* d_ws, size_t ws_size,
                              hipStream_t stream) {
    const float* planes = (const float*)d_in[0];  // (8,3,4) fp32
    const float* pts    = (const float*)d_in[1];  // (8,4096,3) fp32
    float* out          = (float*)d_out;          // scalar fp32

    // reg kernel initializes out[0] (d_out is poisoned 0xAA before each launch)
    reg_kernel<<<1, 64, 0, stream>>>(planes, out);

    dim3 grid(NP / BLK, NB * NH, 2);
    chamfer_kernel<<<grid, BLK, 0, stream>>>(pts, planes, out);
}

// Round 2
// 131.067 us; speedup vs baseline: 1.1736x; 1.1736x over previous
//
#include <hip/hip_runtime.h>
#include <math.h>

#define NB   8
#define NH   3
#define NBH  (NB * NH)          // 24
#define NP   4096
#define BLK  256
#define RPT  4                  // rows per thread
#define CQ   4                  // column quarters
#define CTILE (NP / CQ)         // 1024 columns staged per block
#define WS_ENTRIES (2 * NBH * NP)  // 196608 partial row-min slots

// ---- ordered-int encoding so unsigned atomicMin == float min ----
__device__ __forceinline__ unsigned enc(float f) {
    unsigned u = __float_as_uint(f);
    return (u & 0x80000000u) ? ~u : (u | 0x80000000u);
}
__device__ __forceinline__ float dec(unsigned u) {
    u = (u & 0x80000000u) ? (u & 0x7FFFFFFFu) : ~u;
    return __uint_as_float(u);
}

// out[0] = 25 * sum_b || N_b N_b^T - I ||_F
__global__ void reg_kernel(const float* __restrict__ planes, float* __restrict__ out) {
    int b = threadIdx.x;
    float r = 0.0f;
    if (b < NB) {
        float n[NH][3];
        for (int h = 0; h < NH; ++h) {
            const float* pl = planes + (b * NH + h) * 4;
            float a0 = pl[0], a1 = pl[1], a2 = pl[2];
            float inv = 1.0f / sqrtf(a0 * a0 + a1 * a1 + a2 * a2);
            n[h][0] = a0 * inv; n[h][1] = a1 * inv; n[h][2] = a2 * inv;
        }
        float fro = 0.0f;
        for (int i = 0; i < NH; ++i)
            for (int j = 0; j < NH; ++j) {
                float d = n[i][0] * n[j][0] + n[i][1] * n[j][1] + n[i][2] * n[j][2]
                          - (i == j ? 1.0f : 0.0f);
                fro += d * d;
            }
        r = sqrtf(fro);
    }
    for (int o = 32; o > 0; o >>= 1) r += __shfl_down(r, o);
    if (threadIdx.x == 0) out[0] = 25.0f * r;
}

// grid: x = (col-quarter<<2)|row-tile (16), y = b*NH+h (24), z = dir.
// Each thread owns 4 rows (stride-256); 1024 columns staged once in LDS as
// float4(-2c0,-2c1,-2c2,|c|^2); per column: 1 ds_read_b128 + 4x(3 fma + min).
// Partial min (xsq+min, unclamped) -> ordered-int atomicMin in ws.
__global__ void __launch_bounds__(BLK) chamfer_kernel(const float* __restrict__ pts,
                                                      const float* __restrict__ planes,
                                                      unsigned* __restrict__ ws) {
    __shared__ float4 qs[CTILE];

    const int rt  = blockIdx.x & 3;
    const int cq  = blockIdx.x >> 2;
    const int bh  = blockIdx.y;
    const int b   = bh / NH;
    const int dir = blockIdx.z;

    const float* pl = planes + bh * 4;
    float n0 = pl[0], n1 = pl[1], n2 = pl[2], off = pl[3];
    float inv = 1.0f / sqrtf(n0 * n0 + n1 * n1 + n2 * n2);
    n0 *= inv; n1 *= inv; n2 *= inv;

    const float* bp = pts + (size_t)b * NP * 3;

    // stage 1024 columns (reflected when dir==0)
    const int cbase = cq * CTILE;
    for (int i = threadIdx.x; i < CTILE; i += BLK) {
        const int q = cbase + i;
        float y0 = bp[q * 3 + 0], y1 = bp[q * 3 + 1], y2 = bp[q * 3 + 2];
        if (!dir) {
            float t = 2.0f * (n0 * y0 + n1 * y1 + n2 * y2 + off);
            y0 -= t * n0; y1 -= t * n1; y2 -= t * n2;
        }
        float ysq = y0 * y0 + y1 * y1 + y2 * y2;
        qs[i] = make_float4(-2.0f * y0, -2.0f * y1, -2.0f * y2, ysq);
    }

    // 4 row points per thread (reflected when dir==1)
    float x0[RPT], x1[RPT], x2[RPT], xsq[RPT], m[RPT];
    const int rbase = rt * (BLK * RPT) + threadIdx.x;
    #pragma unroll
    for (int k = 0; k < RPT; ++k) {
        const int r = rbase + k * BLK;
        float a0 = bp[r * 3 + 0], a1 = bp[r * 3 + 1], a2 = bp[r * 3 + 2];
        if (dir) {
            float t = 2.0f * (n0 * a0 + n1 * a1 + n2 * a2 + off);
            a0 -= t * n0; a1 -= t * n1; a2 -= t * n2;
        }
        x0[k] = a0; x1[k] = a1; x2[k] = a2;
        xsq[k] = a0 * a0 + a1 * a1 + a2 * a2;
        m[k] = 1e30f;
    }

    __syncthreads();

    #pragma unroll 4
    for (int i = 0; i < CTILE; ++i) {
        float4 c = qs[i];
        #pragma unroll
        for (int k = 0; k < RPT; ++k) {
            float t = fmaf(x2[k], c.z, fmaf(x1[k], c.y, fmaf(x0[k], c.x, c.w)));
            m[k] = fminf(m[k], t);
        }
    }

    unsigned* wrow = ws + (size_t)(dir * NBH + bh) * NP;
    #pragma unroll
    for (int k = 0; k < RPT; ++k) {
        atomicMin(&wrow[rbase + k * BLK], enc(xsq[k] + m[k]));
    }
}

// decode, clamp, mean over (B,P), sum into out
__global__ void reduce_kernel(const unsigned* __restrict__ ws, float* __restrict__ out) {
    __shared__ float wsum[BLK / 64];
    float s = 0.0f;
    for (int i = blockIdx.x * BLK + threadIdx.x; i < WS_ENTRIES; i += gridDim.x * BLK)
        s += fmaxf(dec(ws[i]), 0.0f);
    for (int o = 32; o > 0; o >>= 1) s += __shfl_down(s, o);
    const int wid = threadIdx.x >> 6;
    if ((threadIdx.x & 63) == 0) wsum[wid] = s;
    __syncthreads();
    if (threadIdx.x == 0) {
        float t = (wsum[0] + wsum[1] + wsum[2] + wsum[3]) * (1.0f / (float)(NB * NP));
        atomicAdd(out, t);
    }
}

extern "C" void kernel_launch(void* const* d_in, const int* in_sizes, int n_in,
                              void* d_out, int out_size, void* d_ws, size_t ws_size,
                              hipStream_t stream) {
    const float* planes = (const float*)d_in[0];  // (8,3,4) fp32
    const float* pts    = (const float*)d_in[1];  // (8,4096,3) fp32
    float* out          = (float*)d_out;
    unsigned* ws        = (unsigned*)d_ws;

    // 0xFF == +inf in the ordered-int encoding
    hipMemsetAsync(ws, 0xFF, WS_ENTRIES * sizeof(unsigned), stream);

    reg_kernel<<<1, 64, 0, stream>>>(planes, out);  // also initializes out[0]

    dim3 grid(CQ * 4, NBH, 2);
    chamfer_kernel<<<grid, BLK, 0, stream>>>(pts, planes, ws);

    reduce_kernel<<<192, BLK, 0, stream>>>(ws, out);
}